// Round 1
// baseline (936.164 us; speedup 1.0000x reference)
//
#include <hip/hip_runtime.h>
#include <stdint.h>
#include <stddef.h>

#define DF 384
#define DP 256
#define NPROT 8
#define NPB 4096
#define KSTEPS 12

typedef __attribute__((ext_vector_type(8))) short bf16x8;
typedef __attribute__((ext_vector_type(4))) float f32x4;

typedef const __attribute__((address_space(1))) unsigned char as1_u8;
typedef __attribute__((address_space(3))) unsigned char as3_u8;

static __device__ __forceinline__ unsigned short f2bf(float f) {
  unsigned int u = __float_as_uint(f);
  u += 0x7fffu + ((u >> 16) & 1u);   // RNE
  return (unsigned short)(u >> 16);
}
static __device__ __forceinline__ float gelu_exact(float x) {
  return 0.5f * x * (1.0f + erff(x * 0.7071067811865476f));
}

// ---------- setup: W_proj [384][256] f32 -> wT [256][384] bf16 ----------
__global__ __launch_bounds__(256) void k_wt(const float* __restrict__ W,
                                            unsigned short* __restrict__ wT) {
  int e = blockIdx.x * 256 + threadIdx.x;       // 0..98303
  int c = e / DF;
  int k = e - c * DF;
  wT[e] = f2bf(W[k * DP + c]);
}

// ---------- setup: l2-normalized prototypes [8][256] ----------
__global__ __launch_bounds__(256) void k_proto(const float* __restrict__ P,
                                               float* __restrict__ PN) {
  __shared__ float s_red[4];
  const int tid = threadIdx.x;
  const int lane = tid & 63, wave = tid >> 6;
  for (int r = 0; r < NPROT; r++) {
    float x = P[r * DP + tid];
    float q = x * x;
    #pragma unroll
    for (int d = 1; d < 64; d <<= 1) q += __shfl_xor(q, d);
    if (lane == 0) s_red[wave] = q;
    __syncthreads();
    float ss = s_red[0] + s_red[1] + s_red[2] + s_red[3];
    PN[r * DP + tid] = x / fmaxf(sqrtf(ss), 1e-12f);
    __syncthreads();
  }
}

// ---------- main fused kernel: 64 rows/block, 4 waves ----------
__global__ __launch_bounds__(256) void k_main(
    const float* __restrict__ patch,
    const float* __restrict__ bias,
    const float* __restrict__ g1,
    const float* __restrict__ beta1,
    const unsigned short* __restrict__ wT,
    const float* __restrict__ protoN,
    float* __restrict__ out_assign,
    float* __restrict__ out_feat,
    float* __restrict__ acc_part,
    float* __restrict__ acc_mass,
    float* __restrict__ acc_pos) {
  __shared__ __align__(16) unsigned char Bbuf[16384];   // 256 cols x 32 k bf16, swizzled
  __shared__ float s_bias[DP], s_g1[DP], s_b1[DP];
  __shared__ float s_proto[NPROT * DP];
  __shared__ float s_part[NPROT * DP];
  __shared__ float s_mass[NPROT], s_px[NPROT], s_py[NPROT];

  const int tid  = threadIdx.x;
  const int lane = tid & 63;
  const int wave = tid >> 6;
  const int mrow = lane & 15;   // M row within wave tile / N col within frag
  const int kgrp = lane >> 4;   // k-chunk selector (8 k's each)

  const long long row0 = (long long)blockIdx.x * 64;
  const int b  = (int)(row0 >> 12);
  const int n0 = (int)(row0 & 4095);

  // cooperative parameter staging (256 threads == DP)
  s_bias[tid] = bias[tid];
  s_g1[tid]   = g1[tid];
  s_b1[tid]   = beta1[tid];
  #pragma unroll
  for (int i = 0; i < NPROT; i++) s_proto[i * DP + tid] = protoN[i * DP + tid];
  #pragma unroll
  for (int i = 0; i < NPROT; i++) s_part[i * DP + tid] = 0.f;
  if (tid < NPROT) { s_mass[tid] = 0.f; s_px[tid] = 0.f; s_py[tid] = 0.f; }

  // ---- A preload: each lane holds row (wave*16+mrow), k = kt*32 + kgrp*8 + j ----
  const float* arow = patch + (size_t)(row0 + wave * 16 + mrow) * DF + kgrp * 8;
  bf16x8 afrag[KSTEPS];
  #pragma unroll
  for (int kt = 0; kt < KSTEPS; kt++) {
    float4 x0 = *(const float4*)(arow + kt * 32);
    float4 x1 = *(const float4*)(arow + kt * 32 + 4);
    bf16x8 a;
    a[0] = (short)f2bf(x0.x); a[1] = (short)f2bf(x0.y);
    a[2] = (short)f2bf(x0.z); a[3] = (short)f2bf(x0.w);
    a[4] = (short)f2bf(x1.x); a[5] = (short)f2bf(x1.y);
    a[6] = (short)f2bf(x1.z); a[7] = (short)f2bf(x1.w);
    afrag[kt] = a;
  }

  f32x4 acc[16];
  #pragma unroll
  for (int f = 0; f < 16; f++) acc[f] = (f32x4){0.f, 0.f, 0.f, 0.f};

  // ---- GEMM main loop: stage B k-slab to LDS (swizzled), 16 MFMAs/wave ----
  #pragma unroll
  for (int kt = 0; kt < KSTEPS; kt++) {
    #pragma unroll
    for (int i = 0; i < 4; i++) {
      int e   = i * 256 + tid;
      int col = e >> 2;
      int t4  = e & 3;
      int sub = t4 ^ (col & 3);                         // source-side swizzle
      const unsigned short* src = wT + col * DF + kt * 32 + sub * 8;
      int lofs = __builtin_amdgcn_readfirstlane((i * 256 + wave * 64) * 16);
      __builtin_amdgcn_global_load_lds((as1_u8*)(const void*)src,
                                       (as3_u8*)(void*)(Bbuf + lofs), 16, 0, 0);
    }
    __syncthreads();
    bf16x8 a = afrag[kt];
    #pragma unroll
    for (int f = 0; f < 16; f++) {
      const int col  = f * 16 + mrow;
      const int slot = kgrp ^ (col & 3);                // read-side swizzle
      bf16x8 bf = *(const bf16x8*)(Bbuf + col * 64 + slot * 16);
      acc[f] = __builtin_amdgcn_mfma_f32_16x16x32_bf16(a, bf, acc[f], 0, 0, 0);
    }
    __syncthreads();
  }

  // ---- epilogue: bias + LayerNorm + GELU (C layout: col=mrow, row=kgrp*4+r) ----
  #pragma unroll
  for (int f = 0; f < 16; f++) {
    const float bb = s_bias[f * 16 + mrow];
    #pragma unroll
    for (int r = 0; r < 4; r++) acc[f][r] += bb;
  }
  #pragma unroll
  for (int r = 0; r < 4; r++) {
    float s = 0.f, q = 0.f;
    #pragma unroll
    for (int f = 0; f < 16; f++) { float x = acc[f][r]; s += x; q += x * x; }
    #pragma unroll
    for (int d = 1; d < 16; d <<= 1) { s += __shfl_xor(s, d); q += __shfl_xor(q, d); }
    const float mean = s * (1.f / 256.f);
    const float var  = q * (1.f / 256.f) - mean * mean;
    const float rstd = rsqrtf(var + 1e-5f);
    #pragma unroll
    for (int f = 0; f < 16; f++) {
      const int col = f * 16 + mrow;
      float y = (acc[f][r] - mean) * rstd * s_g1[col] + s_b1[col];
      acc[f][r] = gelu_exact(y);
    }
  }

  // ---- feat writes ----
  {
    float* fb = out_feat + (size_t)(row0 + wave * 16 + kgrp * 4) * DP;
    #pragma unroll
    for (int r = 0; r < 4; r++) {
      #pragma unroll
      for (int f = 0; f < 16; f++) fb[(size_t)r * DP + f * 16 + mrow] = acc[f][r];
    }
  }

  // ---- l2 norm + prototype dots ----
  float dot[4][NPROT];
  float ss[4];
  #pragma unroll
  for (int r = 0; r < 4; r++) {
    ss[r] = 0.f;
    #pragma unroll
    for (int k = 0; k < NPROT; k++) dot[r][k] = 0.f;
  }
  #pragma unroll
  for (int f = 0; f < 16; f++) {
    float pk[NPROT];
    #pragma unroll
    for (int k = 0; k < NPROT; k++) pk[k] = s_proto[k * DP + f * 16 + mrow];
    #pragma unroll
    for (int r = 0; r < 4; r++) {
      const float gv = acc[f][r];
      ss[r] += gv * gv;
      #pragma unroll
      for (int k = 0; k < NPROT; k++) dot[r][k] += gv * pk[k];
    }
  }

  // ---- reduce, softmax over K=8 ----
  float asg[4][NPROT];
  #pragma unroll
  for (int r = 0; r < 4; r++) {
    float s2 = ss[r];
    #pragma unroll
    for (int d = 1; d < 16; d <<= 1) s2 += __shfl_xor(s2, d);
    #pragma unroll
    for (int k = 0; k < NPROT; k++) {
      float v = dot[r][k];
      #pragma unroll
      for (int d = 1; d < 16; d <<= 1) v += __shfl_xor(v, d);
      dot[r][k] = v;
    }
    const float inv = (1.f / 0.07f) / fmaxf(sqrtf(s2), 1e-12f);
    float mx = -1e30f;
    #pragma unroll
    for (int k = 0; k < NPROT; k++) { dot[r][k] *= inv; mx = fmaxf(mx, dot[r][k]); }
    float se = 0.f;
    #pragma unroll
    for (int k = 0; k < NPROT; k++) { float e = expf(dot[r][k] - mx); asg[r][k] = e; se += e; }
    const float rs = 1.f / se;
    #pragma unroll
    for (int k = 0; k < NPROT; k++) asg[r][k] *= rs;
  }

  // ---- assign writes (lane 0 of each 16-group owns its 4 rows) ----
  #pragma unroll
  for (int r = 0; r < 4; r++) {
    if (mrow == 0) {
      const int n = n0 + wave * 16 + kgrp * 4 + r;
      float4* dst = (float4*)(out_assign + ((size_t)b * NPB + n) * NPROT);
      dst[0] = make_float4(asg[r][0], asg[r][1], asg[r][2], asg[r][3]);
      dst[1] = make_float4(asg[r][4], asg[r][5], asg[r][6], asg[r][7]);
    }
  }

  // ---- mass / position accumulation ----
  float msum[NPROT], pxs[NPROT], pys[NPROT];
  #pragma unroll
  for (int k = 0; k < NPROT; k++) { msum[k] = 0.f; pxs[k] = 0.f; pys[k] = 0.f; }
  #pragma unroll
  for (int r = 0; r < 4; r++) {
    const int n = n0 + wave * 16 + kgrp * 4 + r;
    const float cx = (float)(n & 63) * (1.f / 63.f);
    const float cy = (float)(n >> 6) * (1.f / 63.f);
    #pragma unroll
    for (int k = 0; k < NPROT; k++) {
      const float a = asg[r][k];
      msum[k] += a; pxs[k] += a * cx; pys[k] += a * cy;
    }
  }
  #pragma unroll
  for (int k = 0; k < NPROT; k++) {
    float v = msum[k]; v += __shfl_xor(v, 16); v += __shfl_xor(v, 32);
    float vx = pxs[k]; vx += __shfl_xor(vx, 16); vx += __shfl_xor(vx, 32);
    float vy = pys[k]; vy += __shfl_xor(vy, 16); vy += __shfl_xor(vy, 32);
    if (lane == 0) { atomicAdd(&s_mass[k], v); atomicAdd(&s_px[k], vx); atomicAdd(&s_py[k], vy); }
  }

  // ---- part-feature accumulation: sum_n assign[n][k]*feat[n][col] ----
  #pragma unroll
  for (int f = 0; f < 16; f++) {
    float p[NPROT];
    #pragma unroll
    for (int k = 0; k < NPROT; k++) p[k] = 0.f;
    #pragma unroll
    for (int r = 0; r < 4; r++) {
      const float gv = acc[f][r];
      #pragma unroll
      for (int k = 0; k < NPROT; k++) p[k] += asg[r][k] * gv;
    }
    #pragma unroll
    for (int k = 0; k < NPROT; k++) {
      float v = p[k]; v += __shfl_xor(v, 16); v += __shfl_xor(v, 32);
      if (lane < 16) atomicAdd(&s_part[k * DP + f * 16 + lane], v);
    }
  }
  __syncthreads();

  // ---- flush block partials to global accumulators ----
  float* gp = acc_part + (size_t)b * (NPROT * DP);
  #pragma unroll
  for (int i = 0; i < NPROT; i++) atomicAdd(&gp[i * 256 + tid], s_part[i * 256 + tid]);
  if (tid < NPROT) {
    atomicAdd(&acc_mass[b * NPROT + tid], s_mass[tid]);
    atomicAdd(&acc_pos[(b * NPROT + tid) * 2 + 0], s_px[tid]);
    atomicAdd(&acc_pos[(b * NPROT + tid) * 2 + 1], s_py[tid]);
  }
}

// ---------- per-batch finalize: refine MLP + pos + salience ----------
__global__ __launch_bounds__(256) void k_final(
    const float* __restrict__ acc_part, const float* __restrict__ acc_mass,
    const float* __restrict__ acc_pos,
    const float* __restrict__ g2, const float* __restrict__ beta2,
    const float* __restrict__ W_r1, const float* __restrict__ b_r1,
    const float* __restrict__ W_r2, const float* __restrict__ b_r2,
    const float* __restrict__ W_s1, const float* __restrict__ b_s1,
    const float* __restrict__ W_s2, const float* __restrict__ b_s2,
    float* __restrict__ out_pf, float* __restrict__ out_pos, float* __restrict__ out_sal) {
  __shared__ float s_pf[8 * DP];
  __shared__ float s_h[8 * DP];
  __shared__ float s_t[8 * 512];
  __shared__ float s_pff[8 * DP];
  __shared__ float s_s1v[8 * 64];
  __shared__ float s_m[8];
  __shared__ float s_red[8];
  const int b = blockIdx.x;
  const int tid = threadIdx.x;
  const int lane = tid & 63, wave = tid >> 6;

  if (tid < 8) s_m[tid] = fmaxf(acc_mass[b * 8 + tid], 1e-6f);
  __syncthreads();
  #pragma unroll
  for (int i = 0; i < 8; i++) {
    int idx = i * 256 + tid;
    s_pf[idx] = acc_part[(size_t)b * 2048 + idx] / s_m[i];
  }
  if (tid < 16) out_pos[b * 16 + tid] = acc_pos[b * 16 + tid] / s_m[tid >> 1];
  __syncthreads();

  // LayerNorm per row
  for (int r = 0; r < 8; r++) {
    float x = s_pf[r * DP + tid];
    float s = x, q = x * x;
    #pragma unroll
    for (int d = 1; d < 64; d <<= 1) { s += __shfl_xor(s, d); q += __shfl_xor(q, d); }
    if (lane == 0) { s_red[wave] = s; s_red[4 + wave] = q; }
    __syncthreads();
    float ts = s_red[0] + s_red[1] + s_red[2] + s_red[3];
    float tq = s_red[4] + s_red[5] + s_red[6] + s_red[7];
    float mean = ts * (1.f / 256.f);
    float var  = tq * (1.f / 256.f) - mean * mean;
    s_h[r * DP + tid] = (x - mean) * rsqrtf(var + 1e-5f) * g2[tid] + beta2[tid];
    __syncthreads();
  }

  // r1: [8][256] @ [256][512] -> GELU
  #pragma unroll
  for (int i = 0; i < 2; i++) {
    const int o = i * 256 + tid;
    float a[8];
    #pragma unroll
    for (int r = 0; r < 8; r++) a[r] = 0.f;
    for (int c = 0; c < DP; c++) {
      const float w = W_r1[c * 512 + o];
      #pragma unroll
      for (int r = 0; r < 8; r++) a[r] += s_h[r * DP + c] * w;
    }
    const float bb = b_r1[o];
    #pragma unroll
    for (int r = 0; r < 8; r++) s_t[r * 512 + o] = gelu_exact(a[r] + bb);
  }
  __syncthreads();

  // r2: [8][512] @ [512][256] + residual
  {
    const int o = tid;
    float a[8];
    #pragma unroll
    for (int r = 0; r < 8; r++) a[r] = 0.f;
    for (int c = 0; c < 512; c++) {
      const float w = W_r2[c * DP + o];
      #pragma unroll
      for (int r = 0; r < 8; r++) a[r] += s_t[r * 512 + c] * w;
    }
    const float bb = b_r2[o];
    #pragma unroll
    for (int r = 0; r < 8; r++) {
      float v = s_pf[r * DP + o] + a[r] + bb;
      s_pff[r * DP + o] = v;
      out_pf[(size_t)b * 2048 + r * DP + o] = v;
    }
  }
  __syncthreads();

  // s1: [8][256] @ [256][64] -> GELU
  if (tid < 64) {
    const int o = tid;
    float a[8];
    #pragma unroll
    for (int r = 0; r < 8; r++) a[r] = 0.f;
    for (int c = 0; c < DP; c++) {
      const float w = W_s1[c * 64 + o];
      #pragma unroll
      for (int r = 0; r < 8; r++) a[r] += s_pff[r * DP + c] * w;
    }
    const float bb = b_s1[o];
    #pragma unroll
    for (int r = 0; r < 8; r++) s_s1v[r * 64 + o] = gelu_exact(a[r] + bb);
  }
  __syncthreads();

  // s2 + sigmoid
  if (tid < 8) {
    float a = 0.f;
    for (int c = 0; c < 64; c++) a += s_s1v[tid * 64 + c] * W_s2[c];
    a += b_s2[0];
    out_sal[b * 8 + tid] = 1.f / (1.f + expf(-a));
  }
}

extern "C" void kernel_launch(void* const* d_in, const int* in_sizes, int n_in,
                              void* d_out, int out_size, void* d_ws, size_t ws_size,
                              hipStream_t stream) {
  (void)in_sizes; (void)n_in; (void)out_size; (void)ws_size;
  const float* patch  = (const float*)d_in[0];
  // d_in[1]=H, d_in[2]=W (both 64, hardcoded)
  const float* W_proj = (const float*)d_in[3];
  const float* b_proj = (const float*)d_in[4];
  const float* g1     = (const float*)d_in[5];
  const float* beta1  = (const float*)d_in[6];
  const float* proto  = (const float*)d_in[7];
  const float* g2     = (const float*)d_in[8];
  const float* beta2  = (const float*)d_in[9];
  const float* W_r1   = (const float*)d_in[10];
  const float* b_r1   = (const float*)d_in[11];
  const float* W_r2   = (const float*)d_in[12];
  const float* b_r2   = (const float*)d_in[13];
  const float* W_s1   = (const float*)d_in[14];
  const float* b_s1   = (const float*)d_in[15];
  const float* W_s2   = (const float*)d_in[16];
  const float* b_s2   = (const float*)d_in[17];

  float* out = (float*)d_out;
  float* out_pf     = out;                 // [64,8,256] = 131072
  float* out_pos    = out + 131072;        // [64,8,2]   = 1024
  float* out_assign = out + 132096;        // [64,4096,8]= 2097152
  float* out_sal    = out + 2229248;       // [64,8]     = 512
  float* out_feat   = out + 2229760;       // [64,4096,256] = 67108864

  char* ws = (char*)d_ws;
  unsigned short* wT = (unsigned short*)ws;          // 196608 B
  float* protoN   = (float*)(ws + 196608);           // 8192 B
  float* acc_part = (float*)(ws + 204800);           // 524288 B
  float* acc_mass = (float*)(ws + 729088);           // 2048 B
  float* acc_pos  = (float*)(ws + 731136);           // 4096 B

  hipMemsetAsync(ws + 204800, 0, 530432, stream);
  k_wt<<<384, 256, 0, stream>>>(W_proj, wT);
  k_proto<<<1, 256, 0, stream>>>(proto, protoN);
  k_main<<<4096, 256, 0, stream>>>(patch, b_proj, g1, beta1, wT, protoN,
                                   out_assign, out_feat, acc_part, acc_mass, acc_pos);
  k_final<<<64, 256, 0, stream>>>(acc_part, acc_mass, acc_pos, g2, beta2,
                                  W_r1, b_r1, W_r2, b_r2, W_s1, b_s1, W_s2, b_s2,
                                  out_pf, out_pos, out_sal);
}